// Round 1
// baseline (1463.722 us; speedup 1.0000x reference)
//
#include <hip/hip_runtime.h>
#include <math.h>

#define N_BINSK  500
#define N_SPL    1499
#define N_CELLSK 128
#define N_GOI    300
#define N_HIDK   32
#define N_LATK   64
#define N_FRAGK  50000
#define WIN_A_F  (-10000.0f)
#define AB_F     (20000.0f)

// workspace layout (bytes)
#define WS_H_OFF   0                         // 128*32 floats = 16384 B
#define WS_CNT_OFF 16384                     // 38400 floats  = 153600 B
#define WS_ACC_OFF 169984                    // 2 doubles (acc[0]=logdet, acc[1]=counts-ll)
#define WS_TOTAL   170000

// ---------------------------------------------------------------- MLP + BN
__global__ __launch_bounds__(128) void mlp_kernel(
    const float* __restrict__ latent, const float* __restrict__ W1, const float* __restrict__ b1,
    const float* __restrict__ g1, const float* __restrict__ be1,
    const float* __restrict__ W2, const float* __restrict__ b2,
    const float* __restrict__ g2, const float* __restrict__ be2,
    float* __restrict__ h_out)
{
    __shared__ float A[N_CELLSK][N_HIDK + 1];
    __shared__ float mean_s[N_HIDK], rstd_s[N_HIDK];
    const int c = threadIdx.x;

    float x[N_LATK];
    #pragma unroll
    for (int i = 0; i < N_LATK; ++i) x[i] = latent[c * N_LATK + i];

    for (int j = 0; j < N_HIDK; ++j) {
        float a = b1[j];
        #pragma unroll
        for (int i = 0; i < N_LATK; ++i) a = fmaf(x[i], W1[i * N_HIDK + j], a);
        A[c][j] = fmaxf(a, 0.0f);
    }
    __syncthreads();
    if (c < N_HIDK) {
        float m = 0.f;
        for (int i = 0; i < N_CELLSK; ++i) m += A[i][c];
        m *= (1.0f / N_CELLSK);
        float v = 0.f;
        for (int i = 0; i < N_CELLSK; ++i) { float d = A[i][c] - m; v += d * d; }
        v *= (1.0f / N_CELLSK);
        mean_s[c] = m;
        rstd_s[c] = rsqrtf(v + 1e-5f);
    }
    __syncthreads();
    float hb[N_HIDK];
    #pragma unroll
    for (int j = 0; j < N_HIDK; ++j)
        hb[j] = (A[c][j] - mean_s[j]) * rstd_s[j] * g1[j] + be1[j];
    __syncthreads();

    for (int j = 0; j < N_HIDK; ++j) {
        float a = b2[j];
        #pragma unroll
        for (int i = 0; i < N_HIDK; ++i) a = fmaf(hb[i], W2[i * N_HIDK + j], a);
        A[c][j] = fmaxf(a, 0.0f);
    }
    __syncthreads();
    if (c < N_HIDK) {
        float m = 0.f;
        for (int i = 0; i < N_CELLSK; ++i) m += A[i][c];
        m *= (1.0f / N_CELLSK);
        float v = 0.f;
        for (int i = 0; i < N_CELLSK; ++i) { float d = A[i][c] - m; v += d * d; }
        v *= (1.0f / N_CELLSK);
        mean_s[c] = m;
        rstd_s[c] = rsqrtf(v + 1e-5f);
    }
    __syncthreads();
    #pragma unroll
    for (int j = 0; j < N_HIDK; ++j)
        h_out[c * N_HIDK + j] = (A[c][j] - mean_s[j]) * rstd_s[j] * g2[j] + be2[j];
}

// ---------------------------------------------------------------- counts scatter
__global__ __launch_bounds__(256) void counts_kernel(const int* __restrict__ lcx,
                                                     float* __restrict__ counts)
{
    int f = blockIdx.x * blockDim.x + threadIdx.x;
    if (f < N_FRAGK) atomicAdd(&counts[lcx[f]], 1.0f);
}

// ---------------------------------------------------------------- per-fragment RQS logdet
// 4 fragments per block; one 64-lane wave per fragment.
__global__ __launch_bounds__(256) void frag_kernel(
    const float* __restrict__ coords, const float* __restrict__ h,
    const float* __restrict__ spline_w, const float* __restrict__ mix_spline,
    const int* __restrict__ genes_oi, const int* __restrict__ lcx,
    const int* __restrict__ lgx, double* __restrict__ acc)
{
    const int wave = threadIdx.x >> 6;
    const int lane = threadIdx.x & 63;
    const int f = blockIdx.x * 4 + wave;
    const bool valid = (f < N_FRAGK);
    const int fc = valid ? f : 0;

    __shared__ float sPW[4][N_BINSK + 1];   // exp(uw) then exclusive prefix (PW[500]=total)
    __shared__ float sPH[4][N_BINSK + 1];
    __shared__ float sUD[4][N_BINSK];       // 499 used

    float* PW = sPW[wave];
    float* PH = sPH[wave];
    float* UD = sUD[wave];

    const int cx = lcx[fc];
    const int c  = cx / N_GOI;
    const int gl = lgx[fc];
    const int g  = genes_oi[gl];

    float hc[N_HIDK];
    {
        const float* hrow = h + c * N_HIDK;
        #pragma unroll
        for (int i = 0; i < N_HIDK; ++i) hc[i] = hrow[i];
    }

    const float* swg  = spline_w + (size_t)g * N_HIDK * N_SPL;
    const float* mixg = mix_spline + (size_t)g * N_SPL;

    // Pass A: params + exp
    for (int d = lane; d < N_SPL; d += 64) {
        float a = mixg[d];
        #pragma unroll
        for (int i = 0; i < N_HIDK; ++i) a = fmaf(hc[i], swg[i * N_SPL + d], a);
        if (d < N_BINSK)            PW[d] = expf(a);
        else if (d < 2 * N_BINSK)   PH[d - N_BINSK] = expf(a);
        else                        UD[d - 2 * N_BINSK] = a;
    }
    __syncthreads();

    // In-place exclusive prefix scan of PW and PH (blocked: 8 contiguous per lane)
    {
        const int base = lane * 8;
        #pragma unroll 1
        for (int arr = 0; arr < 2; ++arr) {
            float* P = arr ? PH : PW;
            float v[8], pre[8];
            float run = 0.f;
            #pragma unroll
            for (int k = 0; k < 8; ++k) {
                int i = base + k;
                v[k] = (i < N_BINSK) ? P[i] : 0.f;
                pre[k] = run;
                run += v[k];
            }
            float s = run;
            #pragma unroll
            for (int off = 1; off < 64; off <<= 1) {
                float t = __shfl_up(s, off);
                if (lane >= off) s += t;
            }
            float excl = s - run;
            #pragma unroll
            for (int k = 0; k < 8; ++k) {
                int i = base + k;
                if (i <= N_BINSK) P[i] = excl + pre[k];
            }
        }
    }
    __syncthreads();

    const float SW = PW[N_BINSK];
    const float SH = PH[N_BINSK];
    const float rSH = 0.5f / SH;
    const float rSW = 0.5f / SW;

    float contrib = 0.f;
    #pragma unroll 1
    for (int k = 0; k < 2; ++k) {
        const float val = coords[fc * 2 + k];
        const float y = ((val - WIN_A_F) / AB_F - 0.5f) * 2.0f;
        const bool inside = (y >= -1.0f) && (y <= 1.0f);
        const float yc = fminf(fmaxf(y, -1.0f), 1.0f);

        // wave-parallel search: largest j in [0,500] with ch[j] <= yc
        int best = 0;
        for (int j = lane + 1; j <= N_BINSK; j += 64) {
            float chv = (j == N_BINSK) ? 1.0f
                                       : 2.0f * (0.001f * (float)j + PH[j] * rSH) - 1.0f;
            if (chv <= yc) best = j;
        }
        #pragma unroll
        for (int off = 32; off; off >>= 1) best = max(best, __shfl_xor(best, off));
        const int idx = min(best, N_BINSK - 1);

        const float ch_k  = (idx == 0) ? -1.0f
                          : 2.0f * (0.001f * (float)idx + PH[idx] * rSH) - 1.0f;
        const float ch_k1 = (idx == N_BINSK - 1) ? 1.0f
                          : 2.0f * (0.001f * (float)(idx + 1) + PH[idx + 1] * rSH) - 1.0f;
        const float h_k = ch_k1 - ch_k;

        const float cw_k  = (idx == 0) ? -1.0f
                          : 2.0f * (0.001f * (float)idx + PW[idx] * rSW) - 1.0f;
        const float cw_k1 = (idx == N_BINSK - 1) ? 1.0f
                          : 2.0f * (0.001f * (float)(idx + 1) + PW[idx + 1] * rSW) - 1.0f;
        const float w_k = cw_k1 - cw_k;

        const float d_k  = (idx == 0)            ? 1.0f : 0.001f + log1pf(expf(UD[idx - 1]));
        const float d_k1 = (idx == N_BINSK - 1)  ? 1.0f : 0.001f + log1pf(expf(UD[idx]));

        const float delta = h_k / w_k;
        const float s2 = d_k + d_k1 - 2.0f * delta;
        const float dy = yc - ch_k;
        const float qa = dy * s2 + h_k * (delta - d_k);
        const float qb = h_k * d_k - dy * s2;
        const float qc = -delta * dy;
        const float disc = qb * qb - 4.0f * qa * qc;
        const float root = 2.0f * qc / (-qb - sqrtf(disc));
        const float th1m = root * (1.0f - root);
        const float den = delta + s2 * th1m;
        const float num = delta * delta *
            (d_k1 * root * root + 2.0f * delta * th1m + d_k * (1.0f - root) * (1.0f - root));
        const float lad = logf(num) - 2.0f * logf(den);
        if (inside) contrib -= lad;
    }

    if (lane == 0 && valid) atomicAdd(acc, (double)contrib);
}

// ---------------------------------------------------------------- Poisson counts term
__global__ __launch_bounds__(256) void ll_counts_kernel(
    const float* __restrict__ h, const float* __restrict__ rho_w,
    const float* __restrict__ rho_bias, const float* __restrict__ libsize,
    const int* __restrict__ genes_oi, const int* __restrict__ cells_oi,
    const float* __restrict__ counts, double* __restrict__ acc)
{
    int i = blockIdx.x * blockDim.x + threadIdx.x;
    float v = 0.f;
    if (i < N_CELLSK * N_GOI) {
        const int c = i / N_GOI;
        const int gl = i - c * N_GOI;
        const int g = genes_oi[gl];
        float rho = 0.f;
        #pragma unroll
        for (int j = 0; j < N_HIDK; ++j)
            rho = fmaf(h[c * N_HIDK + j], rho_w[g * N_HIDK + j], rho);
        const float rate = rho_bias[g] * expf(rho) * libsize[cells_oi[c]];
        const float cnt = counts[i];
        v = cnt * logf(rate) - rate - lgammaf(cnt + 1.0f);
    }
    #pragma unroll
    for (int off = 32; off; off >>= 1) v += __shfl_xor(v, off);
    if ((threadIdx.x & 63) == 0) atomicAdd(acc + 1, (double)v);
}

// ---------------------------------------------------------------- finalize
__global__ void final_kernel(const double* __restrict__ acc, float* __restrict__ out)
{
    const double c0 = (double)(2 * N_FRAGK) * (log(0.5) - log((double)AB_F));
    out[0] = (float)(-(acc[0] + c0 + acc[1]));
}

// ---------------------------------------------------------------- launch
extern "C" void kernel_launch(void* const* d_in, const int* in_sizes, int n_in,
                              void* d_out, int out_size, void* d_ws, size_t ws_size,
                              hipStream_t stream)
{
    const float* latent   = (const float*)d_in[0];
    const float* coords   = (const float*)d_in[1];
    const float* W1       = (const float*)d_in[2];
    const float* b1       = (const float*)d_in[3];
    const float* g1       = (const float*)d_in[4];
    const float* be1      = (const float*)d_in[5];
    const float* W2       = (const float*)d_in[6];
    const float* b2       = (const float*)d_in[7];
    const float* g2       = (const float*)d_in[8];
    const float* be2      = (const float*)d_in[9];
    const float* spline_w = (const float*)d_in[10];
    const float* rho_w    = (const float*)d_in[11];
    const float* mix      = (const float*)d_in[12];
    const float* rho_bias = (const float*)d_in[13];
    const float* libsize  = (const float*)d_in[14];
    const int* genes_oi   = (const int*)d_in[15];
    const int* cells_oi   = (const int*)d_in[16];
    const int* lcx        = (const int*)d_in[17];
    const int* lgx        = (const int*)d_in[18];

    float*  h_ws   = (float*)d_ws;
    float*  counts = (float*)((char*)d_ws + WS_CNT_OFF);
    double* acc    = (double*)((char*)d_ws + WS_ACC_OFF);

    hipMemsetAsync(d_ws, 0, WS_TOTAL, stream);

    hipLaunchKernelGGL(mlp_kernel, dim3(1), dim3(128), 0, stream,
                       latent, W1, b1, g1, be1, W2, b2, g2, be2, h_ws);
    hipLaunchKernelGGL(counts_kernel, dim3((N_FRAGK + 255) / 256), dim3(256), 0, stream,
                       lcx, counts);
    hipLaunchKernelGGL(frag_kernel, dim3((N_FRAGK + 3) / 4), dim3(256), 0, stream,
                       coords, h_ws, spline_w, mix, genes_oi, lcx, lgx, acc);
    hipLaunchKernelGGL(ll_counts_kernel, dim3((N_CELLSK * N_GOI + 255) / 256), dim3(256), 0, stream,
                       h_ws, rho_w, rho_bias, libsize, genes_oi, cells_oi, counts, acc);
    hipLaunchKernelGGL(final_kernel, dim3(1), dim3(1), 0, stream, acc, (float*)d_out);
}

// Round 2
// 1200.994 us; speedup vs baseline: 1.2188x; 1.2188x over previous
//
#include <hip/hip_runtime.h>
#include <math.h>

#define N_BINSK  500
#define N_SPL    1499
#define N_CELLSK 128
#define N_GOI    300
#define N_HIDK   32
#define N_LATK   64
#define N_FRAGK  50000
#define N_PAIR   (N_CELLSK * N_GOI)
#define WIN_A_F  (-10000.0f)
#define AB_F     (20000.0f)

#define CELLS_PB 16
#define CSTRIDE  1509   // per-cell floats in P: PW@0 (uses 501 of 504), PH@504 (501), UD@1008 (499)
#define CHUNK    256
#define NPASS    6      // 6*256 = 1536 >= 1499

// ---- workspace layout (bytes) ----
#define WS_HIST  0                                // int[38400]
#define WS_ACC   (WS_HIST + N_PAIR * 4)           // double[2]  (153600, 8-aligned)
#define WS_H     (WS_ACC + 16)                    // float[128*32] (153616, 16-aligned)
#define WS_OFF   (WS_H + N_CELLSK * N_HIDK * 4)   // int[38401]
#define WS_CUR   (WS_OFF + (N_PAIR + 1) * 4)      // int[38400]
#define WS_SORT  (WS_CUR + N_PAIR * 4)            // int[50000]

// ---------------------------------------------------------------- MLP + BN
__global__ __launch_bounds__(128) void mlp_kernel(
    const float* __restrict__ latent, const float* __restrict__ W1, const float* __restrict__ b1,
    const float* __restrict__ g1, const float* __restrict__ be1,
    const float* __restrict__ W2, const float* __restrict__ b2,
    const float* __restrict__ g2, const float* __restrict__ be2,
    float* __restrict__ h_out)
{
    __shared__ float A[N_CELLSK][N_HIDK + 1];
    __shared__ float mean_s[N_HIDK], rstd_s[N_HIDK];
    const int c = threadIdx.x;

    float x[N_LATK];
    #pragma unroll
    for (int i = 0; i < N_LATK; ++i) x[i] = latent[c * N_LATK + i];

    for (int j = 0; j < N_HIDK; ++j) {
        float a = b1[j];
        #pragma unroll
        for (int i = 0; i < N_LATK; ++i) a = fmaf(x[i], W1[i * N_HIDK + j], a);
        A[c][j] = fmaxf(a, 0.0f);
    }
    __syncthreads();
    if (c < N_HIDK) {
        float m = 0.f;
        for (int i = 0; i < N_CELLSK; ++i) m += A[i][c];
        m *= (1.0f / N_CELLSK);
        float v = 0.f;
        for (int i = 0; i < N_CELLSK; ++i) { float d = A[i][c] - m; v += d * d; }
        v *= (1.0f / N_CELLSK);
        mean_s[c] = m;
        rstd_s[c] = rsqrtf(v + 1e-5f);
    }
    __syncthreads();
    float hb[N_HIDK];
    #pragma unroll
    for (int j = 0; j < N_HIDK; ++j)
        hb[j] = (A[c][j] - mean_s[j]) * rstd_s[j] * g1[j] + be1[j];
    __syncthreads();

    for (int j = 0; j < N_HIDK; ++j) {
        float a = b2[j];
        #pragma unroll
        for (int i = 0; i < N_HIDK; ++i) a = fmaf(hb[i], W2[i * N_HIDK + j], a);
        A[c][j] = fmaxf(a, 0.0f);
    }
    __syncthreads();
    if (c < N_HIDK) {
        float m = 0.f;
        for (int i = 0; i < N_CELLSK; ++i) m += A[i][c];
        m *= (1.0f / N_CELLSK);
        float v = 0.f;
        for (int i = 0; i < N_CELLSK; ++i) { float d = A[i][c] - m; v += d * d; }
        v *= (1.0f / N_CELLSK);
        mean_s[c] = m;
        rstd_s[c] = rsqrtf(v + 1e-5f);
    }
    __syncthreads();
    #pragma unroll
    for (int j = 0; j < N_HIDK; ++j)
        h_out[c * N_HIDK + j] = (A[c][j] - mean_s[j]) * rstd_s[j] * g2[j] + be2[j];
}

// ---------------------------------------------------------------- histogram (also Poisson counts)
__global__ __launch_bounds__(256) void hist_kernel(const int* __restrict__ lcx,
                                                   int* __restrict__ hist)
{
    int f = blockIdx.x * blockDim.x + threadIdx.x;
    if (f < N_FRAGK) atomicAdd(&hist[lcx[f]], 1);
}

// ---------------------------------------------------------------- exclusive scan of hist -> off, cur
__global__ __launch_bounds__(1024) void scan_kernel(const int* __restrict__ hist,
                                                    int* __restrict__ off,
                                                    int* __restrict__ cur)
{
    __shared__ int wsum[16];
    const int t = threadIdx.x, lane = t & 63, w = t >> 6;
    const int base = t * 38;
    int loc[38];
    int run = 0;
    #pragma unroll
    for (int k = 0; k < 38; ++k) {
        const int i = base + k;
        const int v = (i < N_PAIR) ? hist[i] : 0;
        loc[k] = run; run += v;
    }
    int s = run;
    #pragma unroll
    for (int o = 1; o < 64; o <<= 1) {
        int tt = __shfl_up(s, o);
        if (lane >= o) s += tt;
    }
    if (lane == 63) wsum[w] = s;
    __syncthreads();
    if (t == 0) {
        int r = 0;
        #pragma unroll
        for (int j = 0; j < 16; ++j) { const int x = wsum[j]; wsum[j] = r; r += x; }
    }
    __syncthreads();
    const int ex = wsum[w] + (s - run);
    #pragma unroll
    for (int k = 0; k < 38; ++k) {
        const int i = base + k;
        if (i < N_PAIR) { off[i] = ex + loc[k]; cur[i] = ex + loc[k]; }
    }
    if (t == 1023) off[N_PAIR] = ex + run;
}

// ---------------------------------------------------------------- scatter fragments sorted by pair
__global__ __launch_bounds__(256) void scatter_kernel(const int* __restrict__ lcx,
                                                      int* __restrict__ cur,
                                                      int* __restrict__ sorted)
{
    int f = blockIdx.x * blockDim.x + threadIdx.x;
    if (f < N_FRAGK) {
        const int p = lcx[f];
        const int pos = atomicAdd(&cur[p], 1);
        sorted[pos] = f;
    }
}

// ---------------------------------------------------------------- fused: per-gene GEMM + scans + fragment logdet
__global__ __launch_bounds__(256, 1) void gene_kernel(
    const float* __restrict__ h, const float* __restrict__ spline_w,
    const float* __restrict__ mix_spline, const int* __restrict__ genes_oi,
    const float* __restrict__ coords, const int* __restrict__ off,
    const int* __restrict__ sorted, double* __restrict__ acc)
{
    __shared__ float P[CELLS_PB * CSTRIDE];   // 96576 B
    __shared__ float Bs[N_HIDK * CHUNK];      // 32768 B

    const int gl = blockIdx.x >> 3;   // gene-of-interest index
    const int ct = blockIdx.x & 7;    // 16-cell tile
    const int g  = genes_oi[gl];
    const int t  = threadIdx.x;
    const int lane = t & 63;
    const int w = t >> 6;

    const int cp  = t & 7;            // cell pair -> cells 2cp, 2cp+1
    const int oct = t >> 3;           // dim octet 0..31

    // h rows for my two cells -> registers
    float h0[N_HIDK], h1[N_HIDK];
    {
        const float4* r0 = (const float4*)(h + (ct * CELLS_PB + 2 * cp) * N_HIDK);
        const float4* r1 = (const float4*)(h + (ct * CELLS_PB + 2 * cp + 1) * N_HIDK);
        #pragma unroll
        for (int q = 0; q < 8; ++q) {
            const float4 a = r0[q], b = r1[q];
            h0[4*q+0]=a.x; h0[4*q+1]=a.y; h0[4*q+2]=a.z; h0[4*q+3]=a.w;
            h1[4*q+0]=b.x; h1[4*q+1]=b.y; h1[4*q+2]=b.z; h1[4*q+3]=b.w;
        }
    }

    const float* swg  = spline_w + (size_t)g * (N_HIDK * N_SPL);
    const float* mixg = mix_spline + (size_t)g * N_SPL;

    #pragma unroll 1
    for (int pass = 0; pass < NPASS; ++pass) {
        const int dbase = pass * CHUNK;
        __syncthreads();                       // Bs readers of previous pass done
        for (int k = t; k < N_HIDK * CHUNK; k += 256) {
            const int i = k >> 8;
            const int d = k & (CHUNK - 1);
            const int dd = dbase + d;
            Bs[k] = (dd < N_SPL) ? swg[i * N_SPL + dd] : 0.f;
        }
        __syncthreads();

        const int d0 = dbase + oct * 8;
        float acc0[8], acc1[8];
        #pragma unroll
        for (int j = 0; j < 8; ++j) {
            const float m = (d0 + j < N_SPL) ? mixg[d0 + j] : 0.f;
            acc0[j] = m; acc1[j] = m;
        }
        #pragma unroll
        for (int i = 0; i < N_HIDK; ++i) {
            const float* bp = &Bs[i * CHUNK + oct * 8];
            const float4 bA = *(const float4*)bp;
            const float4 bB = *(const float4*)(bp + 4);
            const float a0 = h0[i], a1 = h1[i];
            acc0[0]=fmaf(a0,bA.x,acc0[0]); acc0[1]=fmaf(a0,bA.y,acc0[1]);
            acc0[2]=fmaf(a0,bA.z,acc0[2]); acc0[3]=fmaf(a0,bA.w,acc0[3]);
            acc0[4]=fmaf(a0,bB.x,acc0[4]); acc0[5]=fmaf(a0,bB.y,acc0[5]);
            acc0[6]=fmaf(a0,bB.z,acc0[6]); acc0[7]=fmaf(a0,bB.w,acc0[7]);
            acc1[0]=fmaf(a1,bA.x,acc1[0]); acc1[1]=fmaf(a1,bA.y,acc1[1]);
            acc1[2]=fmaf(a1,bA.z,acc1[2]); acc1[3]=fmaf(a1,bA.w,acc1[3]);
            acc1[4]=fmaf(a1,bB.x,acc1[4]); acc1[5]=fmaf(a1,bB.y,acc1[5]);
            acc1[6]=fmaf(a1,bB.z,acc1[6]); acc1[7]=fmaf(a1,bB.w,acc1[7]);
        }
        float* P0 = P + (2 * cp) * CSTRIDE;
        float* P1 = P + (2 * cp + 1) * CSTRIDE;
        #pragma unroll
        for (int j = 0; j < 8; ++j) {
            const int d = d0 + j;
            if (d < N_SPL) {
                if (d < N_BINSK) {
                    P0[d] = expf(acc0[j]);            P1[d] = expf(acc1[j]);
                } else if (d < 2 * N_BINSK) {
                    P0[504 + d - N_BINSK] = expf(acc0[j]);
                    P1[504 + d - N_BINSK] = expf(acc1[j]);
                } else {
                    P0[1008 + d - 2 * N_BINSK] = acc0[j];
                    P1[1008 + d - 2 * N_BINSK] = acc1[j];
                }
            }
        }
    }
    __syncthreads();

    // per-cell exclusive prefix scans of exp(uw), exp(uh); P[...500] gets total
    for (int s = w; s < 2 * CELLS_PB; s += 4) {
        float* Pb = P + (s >> 1) * CSTRIDE + ((s & 1) ? 504 : 0);
        float v[8], pre[8];
        float run = 0.f;
        const int base = lane * 8;
        #pragma unroll
        for (int k = 0; k < 8; ++k) {
            const int i = base + k;
            v[k] = (i < N_BINSK) ? Pb[i] : 0.f;
            pre[k] = run; run += v[k];
        }
        float sv = run;
        #pragma unroll
        for (int o = 1; o < 64; o <<= 1) {
            float tt = __shfl_up(sv, o);
            if (lane >= o) sv += tt;
        }
        const float excl = sv - run;
        #pragma unroll
        for (int k = 0; k < 8; ++k) {
            const int i = base + k;
            if (i <= N_BINSK) Pb[i] = excl + pre[k];
        }
    }
    __syncthreads();

    // fragments of this block's 16 pairs-of-(cell, gene)
    float contrib = 0.f;
    for (int cl = w; cl < CELLS_PB; cl += 4) {
        const int cg = ct * CELLS_PB + cl;
        const int p = cg * N_GOI + gl;
        const int o0 = off[p], o1 = off[p + 1];
        if (o0 >= o1) continue;
        const float* PWc = P + cl * CSTRIDE;
        const float* PHc = PWc + 504;
        const float* UDc = PWc + 1008;
        const float rSW = 0.5f / PWc[N_BINSK];
        const float rSH = 0.5f / PHc[N_BINSK];
        for (int k = o0; k < o1; ++k) {
            const int fid = sorted[k];
            #pragma unroll 1
            for (int q = 0; q < 2; ++q) {
                const float val = coords[fid * 2 + q];
                const float y = ((val - WIN_A_F) / AB_F - 0.5f) * 2.0f;
                if (!(y >= -1.0f && y <= 1.0f)) continue;   // wave-uniform
                const float yc = y;

                int best = 0;
                for (int j = lane + 1; j <= N_BINSK; j += 64) {
                    const float chv = (j == N_BINSK) ? 1.0f
                                    : 2.0f * (0.001f * (float)j + PHc[j] * rSH) - 1.0f;
                    if (chv <= yc) best = j;
                }
                #pragma unroll
                for (int o = 32; o; o >>= 1) best = max(best, __shfl_xor(best, o));
                const int idx = min(best, N_BINSK - 1);

                const float ch_k  = (idx == 0) ? -1.0f
                                  : 2.0f * (0.001f * (float)idx + PHc[idx] * rSH) - 1.0f;
                const float ch_k1 = (idx == N_BINSK - 1) ? 1.0f
                                  : 2.0f * (0.001f * (float)(idx + 1) + PHc[idx + 1] * rSH) - 1.0f;
                const float h_k = ch_k1 - ch_k;

                const float cw_k  = (idx == 0) ? -1.0f
                                  : 2.0f * (0.001f * (float)idx + PWc[idx] * rSW) - 1.0f;
                const float cw_k1 = (idx == N_BINSK - 1) ? 1.0f
                                  : 2.0f * (0.001f * (float)(idx + 1) + PWc[idx + 1] * rSW) - 1.0f;
                const float w_k = cw_k1 - cw_k;

                const float d_k  = (idx == 0)           ? 1.0f : 0.001f + log1pf(expf(UDc[idx - 1]));
                const float d_k1 = (idx == N_BINSK - 1) ? 1.0f : 0.001f + log1pf(expf(UDc[idx]));

                const float delta = h_k / w_k;
                const float s2 = d_k + d_k1 - 2.0f * delta;
                const float dy = yc - ch_k;
                const float qa = dy * s2 + h_k * (delta - d_k);
                const float qb = h_k * d_k - dy * s2;
                const float qc = -delta * dy;
                const float disc = qb * qb - 4.0f * qa * qc;
                const float root = 2.0f * qc / (-qb - sqrtf(disc));
                const float th1m = root * (1.0f - root);
                const float den = delta + s2 * th1m;
                const float num = delta * delta *
                    (d_k1 * root * root + 2.0f * delta * th1m + d_k * (1.0f - root) * (1.0f - root));
                const float lad = logf(num) - 2.0f * logf(den);
                contrib -= lad;
            }
        }
    }
    if (lane == 0) atomicAdd(acc, (double)contrib);
}

// ---------------------------------------------------------------- Poisson counts term
__global__ __launch_bounds__(256) void ll_counts_kernel(
    const float* __restrict__ h, const float* __restrict__ rho_w,
    const float* __restrict__ rho_bias, const float* __restrict__ libsize,
    const int* __restrict__ genes_oi, const int* __restrict__ cells_oi,
    const int* __restrict__ counts, double* __restrict__ acc)
{
    int i = blockIdx.x * blockDim.x + threadIdx.x;
    float v = 0.f;
    if (i < N_PAIR) {
        const int c = i / N_GOI;
        const int gl = i - c * N_GOI;
        const int g = genes_oi[gl];
        float rho = 0.f;
        #pragma unroll
        for (int j = 0; j < N_HIDK; ++j)
            rho = fmaf(h[c * N_HIDK + j], rho_w[g * N_HIDK + j], rho);
        const float rate = rho_bias[g] * expf(rho) * libsize[cells_oi[c]];
        const float cnt = (float)counts[i];
        v = cnt * logf(rate) - rate - lgammaf(cnt + 1.0f);
    }
    #pragma unroll
    for (int o = 32; o; o >>= 1) v += __shfl_xor(v, o);
    if ((threadIdx.x & 63) == 0) atomicAdd(acc + 1, (double)v);
}

// ---------------------------------------------------------------- finalize
__global__ void final_kernel(const double* __restrict__ acc, float* __restrict__ out)
{
    const double c0 = (double)(2 * N_FRAGK) * (log(0.5) - log((double)AB_F));
    out[0] = (float)(-(acc[0] + c0 + acc[1]));
}

// ---------------------------------------------------------------- launch
extern "C" void kernel_launch(void* const* d_in, const int* in_sizes, int n_in,
                              void* d_out, int out_size, void* d_ws, size_t ws_size,
                              hipStream_t stream)
{
    const float* latent   = (const float*)d_in[0];
    const float* coords   = (const float*)d_in[1];
    const float* W1       = (const float*)d_in[2];
    const float* b1       = (const float*)d_in[3];
    const float* g1       = (const float*)d_in[4];
    const float* be1      = (const float*)d_in[5];
    const float* W2       = (const float*)d_in[6];
    const float* b2       = (const float*)d_in[7];
    const float* g2       = (const float*)d_in[8];
    const float* be2      = (const float*)d_in[9];
    const float* spline_w = (const float*)d_in[10];
    const float* rho_w    = (const float*)d_in[11];
    const float* mix      = (const float*)d_in[12];
    const float* rho_bias = (const float*)d_in[13];
    const float* libsize  = (const float*)d_in[14];
    const int* genes_oi   = (const int*)d_in[15];
    const int* cells_oi   = (const int*)d_in[16];
    const int* lcx        = (const int*)d_in[17];

    char* ws = (char*)d_ws;
    int*    hist   = (int*)(ws + WS_HIST);
    double* acc    = (double*)(ws + WS_ACC);
    float*  h_ws   = (float*)(ws + WS_H);
    int*    off    = (int*)(ws + WS_OFF);
    int*    cur    = (int*)(ws + WS_CUR);
    int*    sorted = (int*)(ws + WS_SORT);

    hipMemsetAsync(d_ws, 0, WS_H, stream);   // hist + acc

    hipLaunchKernelGGL(mlp_kernel, dim3(1), dim3(128), 0, stream,
                       latent, W1, b1, g1, be1, W2, b2, g2, be2, h_ws);
    hipLaunchKernelGGL(hist_kernel, dim3((N_FRAGK + 255) / 256), dim3(256), 0, stream,
                       lcx, hist);
    hipLaunchKernelGGL(scan_kernel, dim3(1), dim3(1024), 0, stream, hist, off, cur);
    hipLaunchKernelGGL(scatter_kernel, dim3((N_FRAGK + 255) / 256), dim3(256), 0, stream,
                       lcx, cur, sorted);
    hipLaunchKernelGGL(gene_kernel, dim3(N_GOI * 8), dim3(256), 0, stream,
                       h_ws, spline_w, mix, genes_oi, coords, off, sorted, acc);
    hipLaunchKernelGGL(ll_counts_kernel, dim3((N_PAIR + 255) / 256), dim3(256), 0, stream,
                       h_ws, rho_w, rho_bias, libsize, genes_oi, cells_oi, hist, acc);
    hipLaunchKernelGGL(final_kernel, dim3(1), dim3(1), 0, stream, acc, (float*)d_out);
}

// Round 3
// 517.777 us; speedup vs baseline: 2.8269x; 2.3195x over previous
//
#include <hip/hip_runtime.h>
#include <math.h>

#define N_BINSK  500
#define N_SPL    1499
#define N_CELLSK 128
#define N_GOI    300
#define N_HIDK   32
#define N_LATK   64
#define N_FRAGK  50000
#define N_PAIR   (N_CELLSK * N_GOI)
#define WIN_A_F  (-10000.0f)
#define AB_F     (20000.0f)

#define CELLS_PB 16
#define CSTRIDE  1509   // per-cell floats in P: PW@0 (501 used), PH@504 (501), UD@1008 (499)

// ---- workspace layout (bytes) ----
#define WS_HIST  0                                  // int[38400]
#define WS_ACC   (N_PAIR * 4)                       // double[192]  (153600)
#define WS_H     (WS_ACC + 192 * 8)                 // float[128*32] (155136)
#define WS_OFF   (WS_H + N_CELLSK * N_HIDK * 4)     // int[38401]
#define WS_CUR   (WS_OFF + (N_PAIR + 1) * 4)        // int[38400]
#define WS_SORT  (WS_CUR + N_PAIR * 4)              // int[50000]
#define WS_ZERO  (WS_H)                             // bytes to memset (hist + acc)

// ---------------------------------------------------------------- MLP + BN
__global__ __launch_bounds__(128) void mlp_kernel(
    const float* __restrict__ latent, const float* __restrict__ W1, const float* __restrict__ b1,
    const float* __restrict__ g1, const float* __restrict__ be1,
    const float* __restrict__ W2, const float* __restrict__ b2,
    const float* __restrict__ g2, const float* __restrict__ be2,
    float* __restrict__ h_out)
{
    __shared__ float A[N_CELLSK][N_HIDK + 1];
    __shared__ float mean_s[N_HIDK], rstd_s[N_HIDK];
    const int c = threadIdx.x;

    float x[N_LATK];
    #pragma unroll
    for (int i = 0; i < N_LATK; ++i) x[i] = latent[c * N_LATK + i];

    for (int j = 0; j < N_HIDK; ++j) {
        float a = b1[j];
        #pragma unroll
        for (int i = 0; i < N_LATK; ++i) a = fmaf(x[i], W1[i * N_HIDK + j], a);
        A[c][j] = fmaxf(a, 0.0f);
    }
    __syncthreads();
    if (c < N_HIDK) {
        float m = 0.f;
        for (int i = 0; i < N_CELLSK; ++i) m += A[i][c];
        m *= (1.0f / N_CELLSK);
        float v = 0.f;
        for (int i = 0; i < N_CELLSK; ++i) { float d = A[i][c] - m; v += d * d; }
        v *= (1.0f / N_CELLSK);
        mean_s[c] = m;
        rstd_s[c] = rsqrtf(v + 1e-5f);
    }
    __syncthreads();
    float hb[N_HIDK];
    #pragma unroll
    for (int j = 0; j < N_HIDK; ++j)
        hb[j] = (A[c][j] - mean_s[j]) * rstd_s[j] * g1[j] + be1[j];
    __syncthreads();

    for (int j = 0; j < N_HIDK; ++j) {
        float a = b2[j];
        #pragma unroll
        for (int i = 0; i < N_HIDK; ++i) a = fmaf(hb[i], W2[i * N_HIDK + j], a);
        A[c][j] = fmaxf(a, 0.0f);
    }
    __syncthreads();
    if (c < N_HIDK) {
        float m = 0.f;
        for (int i = 0; i < N_CELLSK; ++i) m += A[i][c];
        m *= (1.0f / N_CELLSK);
        float v = 0.f;
        for (int i = 0; i < N_CELLSK; ++i) { float d = A[i][c] - m; v += d * d; }
        v *= (1.0f / N_CELLSK);
        mean_s[c] = m;
        rstd_s[c] = rsqrtf(v + 1e-5f);
    }
    __syncthreads();
    #pragma unroll
    for (int j = 0; j < N_HIDK; ++j)
        h_out[c * N_HIDK + j] = (A[c][j] - mean_s[j]) * rstd_s[j] * g2[j] + be2[j];
}

// ---------------------------------------------------------------- histogram (also Poisson counts)
__global__ __launch_bounds__(256) void hist_kernel(const int* __restrict__ lcx,
                                                   int* __restrict__ hist)
{
    int f = blockIdx.x * blockDim.x + threadIdx.x;
    if (f < N_FRAGK) atomicAdd(&hist[lcx[f]], 1);
}

// ---------------------------------------------------------------- exclusive scan of hist -> off, cur
__global__ __launch_bounds__(1024) void scan_kernel(const int* __restrict__ hist,
                                                    int* __restrict__ off,
                                                    int* __restrict__ cur)
{
    __shared__ int wsum[16];
    const int t = threadIdx.x, lane = t & 63, w = t >> 6;
    const int base = t * 38;
    int loc[38];
    int run = 0;
    #pragma unroll
    for (int k = 0; k < 38; ++k) {
        const int i = base + k;
        const int v = (i < N_PAIR) ? hist[i] : 0;
        loc[k] = run; run += v;
    }
    int s = run;
    #pragma unroll
    for (int o = 1; o < 64; o <<= 1) {
        int tt = __shfl_up(s, o);
        if (lane >= o) s += tt;
    }
    if (lane == 63) wsum[w] = s;
    __syncthreads();
    if (t == 0) {
        int r = 0;
        #pragma unroll
        for (int j = 0; j < 16; ++j) { const int x = wsum[j]; wsum[j] = r; r += x; }
    }
    __syncthreads();
    const int ex = wsum[w] + (s - run);
    #pragma unroll
    for (int k = 0; k < 38; ++k) {
        const int i = base + k;
        if (i < N_PAIR) { off[i] = ex + loc[k]; cur[i] = ex + loc[k]; }
    }
    if (t == 1023) off[N_PAIR] = ex + run;
}

// ---------------------------------------------------------------- scatter fragments sorted by pair
__global__ __launch_bounds__(256) void scatter_kernel(const int* __restrict__ lcx,
                                                      int* __restrict__ cur,
                                                      int* __restrict__ sorted)
{
    int f = blockIdx.x * blockDim.x + threadIdx.x;
    if (f < N_FRAGK) {
        const int p = lcx[f];
        const int pos = atomicAdd(&cur[p], 1);
        sorted[pos] = f;
    }
}

__device__ __forceinline__ void store_param(float* Pc, int d, float v)
{
    if (d < N_BINSK)             Pc[d] = expf(v);
    else if (d < 2 * N_BINSK)    Pc[504 + (d - N_BINSK)] = expf(v);
    else                         Pc[1008 + (d - 2 * N_BINSK)] = v;
}

// ---------------------------------------------------------------- fused: per-gene GEMM + scans + fragment logdet
// 512 threads; GEMM: thread t owns dims [3t, 3t+3) x 16 cells, B streamed global->reg.
__global__ __launch_bounds__(512, 1) void gene_kernel(
    const float* __restrict__ h, const float* __restrict__ spline_w,
    const float* __restrict__ mix_spline, const int* __restrict__ genes_oi,
    const float* __restrict__ coords, const int* __restrict__ off,
    const int* __restrict__ sorted, double* __restrict__ acc)
{
    __shared__ float P[CELLS_PB * CSTRIDE];                 // 96576 B
    __shared__ __align__(16) float hs[N_HIDK][CELLS_PB];    // 2048 B

    const int gl = blockIdx.x >> 3;   // gene-of-interest index
    const int ct = blockIdx.x & 7;    // 16-cell tile
    const int g  = genes_oi[gl];
    const int t  = threadIdx.x;
    const int lane = t & 63;
    const int w = t >> 6;

    {
        const int c = t & 15, i = t >> 4;   // 32*16 = 512 = blockDim
        hs[i][c] = h[(ct * CELLS_PB + c) * N_HIDK + i];
    }
    __syncthreads();

    if (t < 500) {
        const int d0 = 3 * t;
        const int e1 = (d0 + 1 < N_SPL) ? 1 : 0;
        const int e2 = (d0 + 2 < N_SPL) ? 2 : 0;
        const float* mixg = mix_spline + (size_t)g * N_SPL + d0;
        const float m0 = mixg[0], m1 = mixg[e1], m2 = mixg[e2];
        float a0[CELLS_PB], a1[CELLS_PB], a2[CELLS_PB];
        #pragma unroll
        for (int c = 0; c < CELLS_PB; ++c) { a0[c] = m0; a1[c] = m1; a2[c] = m2; }

        const float* bp = spline_w + (size_t)g * (N_HIDK * N_SPL) + d0;
        #pragma unroll 4
        for (int i = 0; i < N_HIDK; ++i) {
            const float b0 = bp[0];
            const float b1 = bp[e1];
            const float b2 = bp[e2];
            bp += N_SPL;
            const float4 hA = *(const float4*)&hs[i][0];
            const float4 hB = *(const float4*)&hs[i][4];
            const float4 hC = *(const float4*)&hs[i][8];
            const float4 hD = *(const float4*)&hs[i][12];
            #define STEP(hv,c) a0[c]=fmaf(hv,b0,a0[c]); a1[c]=fmaf(hv,b1,a1[c]); a2[c]=fmaf(hv,b2,a2[c]);
            STEP(hA.x, 0) STEP(hA.y, 1) STEP(hA.z, 2)  STEP(hA.w, 3)
            STEP(hB.x, 4) STEP(hB.y, 5) STEP(hB.z, 6)  STEP(hB.w, 7)
            STEP(hC.x, 8) STEP(hC.y, 9) STEP(hC.z, 10) STEP(hC.w, 11)
            STEP(hD.x,12) STEP(hD.y,13) STEP(hD.z, 14) STEP(hD.w, 15)
            #undef STEP
        }
        #pragma unroll
        for (int c = 0; c < CELLS_PB; ++c) {
            float* Pc = P + c * CSTRIDE;
            store_param(Pc, d0, a0[c]);
            if (e1) store_param(Pc, d0 + 1, a1[c]);
            if (e2) store_param(Pc, d0 + 2, a2[c]);
        }
    }
    __syncthreads();

    // per-cell exclusive prefix scans of exp(uw), exp(uh); P[...][500] gets total
    for (int s = w; s < 2 * CELLS_PB; s += 8) {
        float* Pb = P + (s >> 1) * CSTRIDE + ((s & 1) ? 504 : 0);
        float v[8], pre[8];
        float run = 0.f;
        const int base = lane * 8;
        #pragma unroll
        for (int k = 0; k < 8; ++k) {
            const int i = base + k;
            v[k] = (i < N_BINSK) ? Pb[i] : 0.f;
            pre[k] = run; run += v[k];
        }
        float sv = run;
        #pragma unroll
        for (int o = 1; o < 64; o <<= 1) {
            float tt = __shfl_up(sv, o);
            if (lane >= o) sv += tt;
        }
        const float excl = sv - run;
        #pragma unroll
        for (int k = 0; k < 8; ++k) {
            const int i = base + k;
            if (i <= N_BINSK) Pb[i] = excl + pre[k];
        }
    }
    __syncthreads();

    // fragments of this block's 16 (cell, gene) pairs; 2 pairs per wave
    float contrib = 0.f;
    for (int cl = w; cl < CELLS_PB; cl += 8) {
        const int cg = ct * CELLS_PB + cl;
        const int p = cg * N_GOI + gl;
        const int o0 = off[p], o1 = off[p + 1];
        if (o0 >= o1) continue;
        const float* PWc = P + cl * CSTRIDE;
        const float* PHc = PWc + 504;
        const float* UDc = PWc + 1008;
        const float rSW = 0.5f / PWc[N_BINSK];
        const float rSH = 0.5f / PHc[N_BINSK];
        for (int k = o0; k < o1; ++k) {
            const int fid = sorted[k];
            #pragma unroll 1
            for (int q = 0; q < 2; ++q) {
                const float val = coords[fid * 2 + q];
                const float y = ((val - WIN_A_F) / AB_F - 0.5f) * 2.0f;
                if (!(y >= -1.0f && y <= 1.0f)) continue;   // wave-uniform
                const float yc = y;

                int best = 0;
                for (int j = lane + 1; j <= N_BINSK; j += 64) {
                    const float chv = (j == N_BINSK) ? 1.0f
                                    : 2.0f * (0.001f * (float)j + PHc[j] * rSH) - 1.0f;
                    if (chv <= yc) best = j;
                }
                #pragma unroll
                for (int o = 32; o; o >>= 1) best = max(best, __shfl_xor(best, o));
                const int idx = min(best, N_BINSK - 1);

                const float ch_k  = (idx == 0) ? -1.0f
                                  : 2.0f * (0.001f * (float)idx + PHc[idx] * rSH) - 1.0f;
                const float ch_k1 = (idx == N_BINSK - 1) ? 1.0f
                                  : 2.0f * (0.001f * (float)(idx + 1) + PHc[idx + 1] * rSH) - 1.0f;
                const float h_k = ch_k1 - ch_k;

                const float cw_k  = (idx == 0) ? -1.0f
                                  : 2.0f * (0.001f * (float)idx + PWc[idx] * rSW) - 1.0f;
                const float cw_k1 = (idx == N_BINSK - 1) ? 1.0f
                                  : 2.0f * (0.001f * (float)(idx + 1) + PWc[idx + 1] * rSW) - 1.0f;
                const float w_k = cw_k1 - cw_k;

                const float d_k  = (idx == 0)           ? 1.0f : 0.001f + log1pf(expf(UDc[idx - 1]));
                const float d_k1 = (idx == N_BINSK - 1) ? 1.0f : 0.001f + log1pf(expf(UDc[idx]));

                const float delta = h_k / w_k;
                const float s2 = d_k + d_k1 - 2.0f * delta;
                const float dy = yc - ch_k;
                const float qa = dy * s2 + h_k * (delta - d_k);
                const float qb = h_k * d_k - dy * s2;
                const float qc = -delta * dy;
                const float disc = qb * qb - 4.0f * qa * qc;
                const float root = 2.0f * qc / (-qb - sqrtf(disc));
                const float th1m = root * (1.0f - root);
                const float den = delta + s2 * th1m;
                const float num = delta * delta *
                    (d_k1 * root * root + 2.0f * delta * th1m + d_k * (1.0f - root) * (1.0f - root));
                const float lad = logf(num) - 2.0f * logf(den);
                contrib -= lad;
            }
        }
    }
    if (lane == 0)
        atomicAdd(&acc[((blockIdx.x << 3) | w) & 127], (double)contrib);
}

// ---------------------------------------------------------------- Poisson counts term
__global__ __launch_bounds__(256) void ll_counts_kernel(
    const float* __restrict__ h, const float* __restrict__ rho_w,
    const float* __restrict__ rho_bias, const float* __restrict__ libsize,
    const int* __restrict__ genes_oi, const int* __restrict__ cells_oi,
    const int* __restrict__ counts, double* __restrict__ acc)
{
    int i = blockIdx.x * blockDim.x + threadIdx.x;
    float v = 0.f;
    if (i < N_PAIR) {
        const int c = i / N_GOI;
        const int gl = i - c * N_GOI;
        const int g = genes_oi[gl];
        float rho = 0.f;
        #pragma unroll
        for (int j = 0; j < N_HIDK; ++j)
            rho = fmaf(h[c * N_HIDK + j], rho_w[g * N_HIDK + j], rho);
        const float rate = rho_bias[g] * expf(rho) * libsize[cells_oi[c]];
        const float cnt = (float)counts[i];
        v = cnt * logf(rate) - rate - lgammaf(cnt + 1.0f);
    }
    #pragma unroll
    for (int o = 32; o; o >>= 1) v += __shfl_xor(v, o);
    if ((threadIdx.x & 63) == 0)
        atomicAdd(&acc[128 + (((blockIdx.x << 2) | (threadIdx.x >> 6)) & 63)], (double)v);
}

// ---------------------------------------------------------------- finalize
__global__ void final_kernel(const double* __restrict__ acc, float* __restrict__ out)
{
    double s = 0.0;
    for (int i = 0; i < 192; ++i) s += acc[i];
    const double c0 = (double)(2 * N_FRAGK) * (log(0.5) - log((double)AB_F));
    out[0] = (float)(-(s + c0));
}

// ---------------------------------------------------------------- launch
extern "C" void kernel_launch(void* const* d_in, const int* in_sizes, int n_in,
                              void* d_out, int out_size, void* d_ws, size_t ws_size,
                              hipStream_t stream)
{
    const float* latent   = (const float*)d_in[0];
    const float* coords   = (const float*)d_in[1];
    const float* W1       = (const float*)d_in[2];
    const float* b1       = (const float*)d_in[3];
    const float* g1       = (const float*)d_in[4];
    const float* be1      = (const float*)d_in[5];
    const float* W2       = (const float*)d_in[6];
    const float* b2       = (const float*)d_in[7];
    const float* g2       = (const float*)d_in[8];
    const float* be2      = (const float*)d_in[9];
    const float* spline_w = (const float*)d_in[10];
    const float* rho_w    = (const float*)d_in[11];
    const float* mix      = (const float*)d_in[12];
    const float* rho_bias = (const float*)d_in[13];
    const float* libsize  = (const float*)d_in[14];
    const int* genes_oi   = (const int*)d_in[15];
    const int* cells_oi   = (const int*)d_in[16];
    const int* lcx        = (const int*)d_in[17];

    char* ws = (char*)d_ws;
    int*    hist   = (int*)(ws + WS_HIST);
    double* acc    = (double*)(ws + WS_ACC);
    float*  h_ws   = (float*)(ws + WS_H);
    int*    off    = (int*)(ws + WS_OFF);
    int*    cur    = (int*)(ws + WS_CUR);
    int*    sorted = (int*)(ws + WS_SORT);

    hipMemsetAsync(d_ws, 0, WS_ZERO, stream);   // hist + acc

    hipLaunchKernelGGL(mlp_kernel, dim3(1), dim3(128), 0, stream,
                       latent, W1, b1, g1, be1, W2, b2, g2, be2, h_ws);
    hipLaunchKernelGGL(hist_kernel, dim3((N_FRAGK + 255) / 256), dim3(256), 0, stream,
                       lcx, hist);
    hipLaunchKernelGGL(scan_kernel, dim3(1), dim3(1024), 0, stream, hist, off, cur);
    hipLaunchKernelGGL(scatter_kernel, dim3((N_FRAGK + 255) / 256), dim3(256), 0, stream,
                       lcx, cur, sorted);
    hipLaunchKernelGGL(gene_kernel, dim3(N_GOI * 8), dim3(512), 0, stream,
                       h_ws, spline_w, mix, genes_oi, coords, off, sorted, acc);
    hipLaunchKernelGGL(ll_counts_kernel, dim3((N_PAIR + 255) / 256), dim3(256), 0, stream,
                       h_ws, rho_w, rho_bias, libsize, genes_oi, cells_oi, hist, acc);
    hipLaunchKernelGGL(final_kernel, dim3(1), dim3(1), 0, stream, acc, (float*)d_out);
}

// Round 4
// 336.096 us; speedup vs baseline: 4.3551x; 1.5406x over previous
//
#include <hip/hip_runtime.h>
#include <math.h>

#define N_BINSK  500
#define N_SPL    1499
#define N_CELLSK 128
#define N_GOI    300
#define N_HIDK   32
#define N_LATK   64
#define N_FRAGK  50000
#define N_PAIR   (N_CELLSK * N_GOI)
#define WIN_A_F  (-10000.0f)
#define AB_F     (20000.0f)

#define CELLS_PB 8
#define N_TILES  (N_CELLSK / CELLS_PB)    // 16
#define CSTRIDE  1509   // per-cell floats in P: PW@0 (501 used), PH@504 (501), UD@1008 (499)

// ---- workspace layout (bytes) ----
#define WS_HIST  0                                  // int[38400]
#define WS_ACC   (N_PAIR * 4)                       // double[192]  (153600)
#define WS_H     (WS_ACC + 192 * 8)                 // float[128*32] (155136)
#define WS_OFF   (WS_H + N_CELLSK * N_HIDK * 4)     // int[38401]
#define WS_CUR   (WS_OFF + (N_PAIR + 1) * 4)        // int[38400]
#define WS_SORT  (WS_CUR + N_PAIR * 4)              // int[50000]
#define WS_ZERO  (WS_H)                             // bytes to memset (hist + acc)

#define HIST_BLOCKS 196   // 196*256 = 50176 >= 50000; block 196 runs the MLP

// ---------------------------------------------------------------- MLP (block HIST_BLOCKS) + histogram
__global__ __launch_bounds__(256) void mlp_hist_kernel(
    const float* __restrict__ latent, const float* __restrict__ W1, const float* __restrict__ b1,
    const float* __restrict__ g1, const float* __restrict__ be1,
    const float* __restrict__ W2, const float* __restrict__ b2,
    const float* __restrict__ g2, const float* __restrict__ be2,
    float* __restrict__ h_out, const int* __restrict__ lcx, int* __restrict__ hist)
{
    if (blockIdx.x < HIST_BLOCKS) {
        const int f = blockIdx.x * 256 + threadIdx.x;
        if (f < N_FRAGK) atomicAdd(&hist[lcx[f]], 1);
        return;
    }
    // ---- MLP block: 256 threads, cells handled by threads < 128 ----
    __shared__ float A[N_CELLSK][N_HIDK + 1];
    __shared__ float mean_s[N_HIDK], rstd_s[N_HIDK];
    const int c = threadIdx.x;
    const bool act = (c < N_CELLSK);

    float x[N_LATK];
    if (act) {
        #pragma unroll
        for (int i = 0; i < N_LATK; ++i) x[i] = latent[c * N_LATK + i];
        for (int j = 0; j < N_HIDK; ++j) {
            float a = b1[j];
            #pragma unroll
            for (int i = 0; i < N_LATK; ++i) a = fmaf(x[i], W1[i * N_HIDK + j], a);
            A[c][j] = fmaxf(a, 0.0f);
        }
    }
    __syncthreads();
    if (c < N_HIDK) {
        float m = 0.f;
        for (int i = 0; i < N_CELLSK; ++i) m += A[i][c];
        m *= (1.0f / N_CELLSK);
        float v = 0.f;
        for (int i = 0; i < N_CELLSK; ++i) { float d = A[i][c] - m; v += d * d; }
        v *= (1.0f / N_CELLSK);
        mean_s[c] = m;
        rstd_s[c] = rsqrtf(v + 1e-5f);
    }
    __syncthreads();
    float hb[N_HIDK];
    if (act) {
        #pragma unroll
        for (int j = 0; j < N_HIDK; ++j)
            hb[j] = (A[c][j] - mean_s[j]) * rstd_s[j] * g1[j] + be1[j];
    }
    __syncthreads();
    if (act) {
        for (int j = 0; j < N_HIDK; ++j) {
            float a = b2[j];
            #pragma unroll
            for (int i = 0; i < N_HIDK; ++i) a = fmaf(hb[i], W2[i * N_HIDK + j], a);
            A[c][j] = fmaxf(a, 0.0f);
        }
    }
    __syncthreads();
    if (c < N_HIDK) {
        float m = 0.f;
        for (int i = 0; i < N_CELLSK; ++i) m += A[i][c];
        m *= (1.0f / N_CELLSK);
        float v = 0.f;
        for (int i = 0; i < N_CELLSK; ++i) { float d = A[i][c] - m; v += d * d; }
        v *= (1.0f / N_CELLSK);
        mean_s[c] = m;
        rstd_s[c] = rsqrtf(v + 1e-5f);
    }
    __syncthreads();
    if (act) {
        #pragma unroll
        for (int j = 0; j < N_HIDK; ++j)
            h_out[c * N_HIDK + j] = (A[c][j] - mean_s[j]) * rstd_s[j] * g2[j] + be2[j];
    }
}

// ---------------------------------------------------------------- exclusive scan of hist -> off, cur
__global__ __launch_bounds__(1024) void scan_kernel(const int* __restrict__ hist,
                                                    int* __restrict__ off,
                                                    int* __restrict__ cur)
{
    __shared__ int wsum[16];
    const int t = threadIdx.x, lane = t & 63, w = t >> 6;
    const int base = t * 38;
    int loc[38];
    int run = 0;
    #pragma unroll
    for (int k = 0; k < 38; ++k) {
        const int i = base + k;
        const int v = (i < N_PAIR) ? hist[i] : 0;
        loc[k] = run; run += v;
    }
    int s = run;
    #pragma unroll
    for (int o = 1; o < 64; o <<= 1) {
        int tt = __shfl_up(s, o);
        if (lane >= o) s += tt;
    }
    if (lane == 63) wsum[w] = s;
    __syncthreads();
    if (t == 0) {
        int r = 0;
        #pragma unroll
        for (int j = 0; j < 16; ++j) { const int x = wsum[j]; wsum[j] = r; r += x; }
    }
    __syncthreads();
    const int ex = wsum[w] + (s - run);
    #pragma unroll
    for (int k = 0; k < 38; ++k) {
        const int i = base + k;
        if (i < N_PAIR) { off[i] = ex + loc[k]; cur[i] = ex + loc[k]; }
    }
    if (t == 1023) off[N_PAIR] = ex + run;
}

// ---------------------------------------------------------------- scatter fragments sorted by pair
__global__ __launch_bounds__(256) void scatter_kernel(const int* __restrict__ lcx,
                                                      int* __restrict__ cur,
                                                      int* __restrict__ sorted)
{
    int f = blockIdx.x * blockDim.x + threadIdx.x;
    if (f < N_FRAGK) {
        const int p = lcx[f];
        const int pos = atomicAdd(&cur[p], 1);
        sorted[pos] = f;
    }
}

__device__ __forceinline__ void store_param(float* Pc, int d, float v)
{
    if (d < N_BINSK)             Pc[d] = expf(v);
    else if (d < 2 * N_BINSK)    Pc[504 + (d - N_BINSK)] = expf(v);
    else                         Pc[1008 + (d - 2 * N_BINSK)] = v;
}

// ---------------------------------------------------------------- fused: per-gene GEMM + scans + fragment logdet
// 512 threads, 8 cells per block. GEMM: thread t<499 owns dims [3t,3t+3) x 8 cells.
__global__ __launch_bounds__(512, 8) void gene_kernel(
    const float* __restrict__ h, const float* __restrict__ spline_w,
    const float* __restrict__ mix_spline, const int* __restrict__ genes_oi,
    const float* __restrict__ coords, const int* __restrict__ off,
    const int* __restrict__ sorted, double* __restrict__ acc)
{
    __shared__ float P[CELLS_PB * CSTRIDE];                 // 48288 B
    __shared__ __align__(16) float hs[N_HIDK][CELLS_PB];    // 1024 B

    const int gl = blockIdx.x >> 4;   // gene-of-interest index
    const int ct = blockIdx.x & 15;   // 8-cell tile
    const int g  = genes_oi[gl];
    const int t  = threadIdx.x;
    const int lane = t & 63;
    const int w = t >> 6;

    if (t < N_HIDK * CELLS_PB) {
        const int c = t & (CELLS_PB - 1), i = t >> 3;
        hs[i][c] = h[(ct * CELLS_PB + c) * N_HIDK + i];
    }
    __syncthreads();

    const float* swg  = spline_w + (size_t)g * (N_HIDK * N_SPL);
    const float* mixg = mix_spline + (size_t)g * N_SPL;

    if (t < 499) {
        const int d0 = 3 * t;
        const float m0 = mixg[d0], m1 = mixg[d0 + 1], m2 = mixg[d0 + 2];
        float a0[CELLS_PB], a1[CELLS_PB], a2[CELLS_PB];
        #pragma unroll
        for (int c = 0; c < CELLS_PB; ++c) { a0[c] = m0; a1[c] = m1; a2[c] = m2; }

        const float* bp = swg + d0;
        #pragma unroll 4
        for (int i = 0; i < N_HIDK; ++i) {
            const float b0 = bp[0];
            const float b1 = bp[1];
            const float b2 = bp[2];
            bp += N_SPL;
            const float4 hA = *(const float4*)&hs[i][0];
            const float4 hB = *(const float4*)&hs[i][4];
            #define STEP(hv,c) a0[c]=fmaf(hv,b0,a0[c]); a1[c]=fmaf(hv,b1,a1[c]); a2[c]=fmaf(hv,b2,a2[c]);
            STEP(hA.x, 0) STEP(hA.y, 1) STEP(hA.z, 2) STEP(hA.w, 3)
            STEP(hB.x, 4) STEP(hB.y, 5) STEP(hB.z, 6) STEP(hB.w, 7)
            #undef STEP
        }
        #pragma unroll
        for (int c = 0; c < CELLS_PB; ++c) {
            float* Pc = P + c * CSTRIDE;
            store_param(Pc, d0,     a0[c]);
            store_param(Pc, d0 + 1, a1[c]);
            store_param(Pc, d0 + 2, a2[c]);
        }
    } else if (t == 499) {
        const int d0 = 1497;   // dims 1497, 1498
        const float m0 = mixg[d0], m1 = mixg[d0 + 1];
        float a0[CELLS_PB], a1[CELLS_PB];
        #pragma unroll
        for (int c = 0; c < CELLS_PB; ++c) { a0[c] = m0; a1[c] = m1; }
        const float* bp = swg + d0;
        #pragma unroll 4
        for (int i = 0; i < N_HIDK; ++i) {
            const float b0 = bp[0];
            const float b1 = bp[1];
            bp += N_SPL;
            const float4 hA = *(const float4*)&hs[i][0];
            const float4 hB = *(const float4*)&hs[i][4];
            #define STEP(hv,c) a0[c]=fmaf(hv,b0,a0[c]); a1[c]=fmaf(hv,b1,a1[c]);
            STEP(hA.x, 0) STEP(hA.y, 1) STEP(hA.z, 2) STEP(hA.w, 3)
            STEP(hB.x, 4) STEP(hB.y, 5) STEP(hB.z, 6) STEP(hB.w, 7)
            #undef STEP
        }
        #pragma unroll
        for (int c = 0; c < CELLS_PB; ++c) {
            float* Pc = P + c * CSTRIDE;
            store_param(Pc, d0,     a0[c]);
            store_param(Pc, d0 + 1, a1[c]);
        }
    }
    __syncthreads();

    // per-cell exclusive prefix scans of exp(uw), exp(uh); P[...][500] gets total
    for (int s = w; s < 2 * CELLS_PB; s += 8) {
        float* Pb = P + (s >> 1) * CSTRIDE + ((s & 1) ? 504 : 0);
        float v[8], pre[8];
        float run = 0.f;
        const int base = lane * 8;
        #pragma unroll
        for (int k = 0; k < 8; ++k) {
            const int i = base + k;
            v[k] = (i < N_BINSK) ? Pb[i] : 0.f;
            pre[k] = run; run += v[k];
        }
        float sv = run;
        #pragma unroll
        for (int o = 1; o < 64; o <<= 1) {
            float tt = __shfl_up(sv, o);
            if (lane >= o) sv += tt;
        }
        const float excl = sv - run;
        #pragma unroll
        for (int k = 0; k < 8; ++k) {
            const int i = base + k;
            if (i <= N_BINSK) Pb[i] = excl + pre[k];
        }
    }
    __syncthreads();

    // fragments: one (cell, gene) pair per wave
    float contrib = 0.f;
    {
        const int cl = w;
        const int cg = ct * CELLS_PB + cl;
        const int p = cg * N_GOI + gl;
        const int o0 = off[p], o1 = off[p + 1];
        if (o0 < o1) {
            const float* PWc = P + cl * CSTRIDE;
            const float* PHc = PWc + 504;
            const float* UDc = PWc + 1008;
            const float rSW = 0.5f / PWc[N_BINSK];
            const float rSH = 0.5f / PHc[N_BINSK];
            for (int k = o0; k < o1; ++k) {
                const int fid = sorted[k];
                #pragma unroll 1
                for (int q = 0; q < 2; ++q) {
                    const float val = coords[fid * 2 + q];
                    const float y = ((val - WIN_A_F) / AB_F - 0.5f) * 2.0f;
                    if (!(y >= -1.0f && y <= 1.0f)) continue;   // wave-uniform
                    const float yc = y;

                    int best = 0;
                    for (int j = lane + 1; j <= N_BINSK; j += 64) {
                        const float chv = (j == N_BINSK) ? 1.0f
                                        : 2.0f * (0.001f * (float)j + PHc[j] * rSH) - 1.0f;
                        if (chv <= yc) best = j;
                    }
                    #pragma unroll
                    for (int o = 32; o; o >>= 1) best = max(best, __shfl_xor(best, o));
                    const int idx = min(best, N_BINSK - 1);

                    const float ch_k  = (idx == 0) ? -1.0f
                                      : 2.0f * (0.001f * (float)idx + PHc[idx] * rSH) - 1.0f;
                    const float ch_k1 = (idx == N_BINSK - 1) ? 1.0f
                                      : 2.0f * (0.001f * (float)(idx + 1) + PHc[idx + 1] * rSH) - 1.0f;
                    const float h_k = ch_k1 - ch_k;

                    const float cw_k  = (idx == 0) ? -1.0f
                                      : 2.0f * (0.001f * (float)idx + PWc[idx] * rSW) - 1.0f;
                    const float cw_k1 = (idx == N_BINSK - 1) ? 1.0f
                                      : 2.0f * (0.001f * (float)(idx + 1) + PWc[idx + 1] * rSW) - 1.0f;
                    const float w_k = cw_k1 - cw_k;

                    const float d_k  = (idx == 0)           ? 1.0f : 0.001f + log1pf(expf(UDc[idx - 1]));
                    const float d_k1 = (idx == N_BINSK - 1) ? 1.0f : 0.001f + log1pf(expf(UDc[idx]));

                    const float delta = h_k / w_k;
                    const float s2 = d_k + d_k1 - 2.0f * delta;
                    const float dy = yc - ch_k;
                    const float qa = dy * s2 + h_k * (delta - d_k);
                    const float qb = h_k * d_k - dy * s2;
                    const float qc = -delta * dy;
                    const float disc = qb * qb - 4.0f * qa * qc;
                    const float root = 2.0f * qc / (-qb - sqrtf(disc));
                    const float th1m = root * (1.0f - root);
                    const float den = delta + s2 * th1m;
                    const float num = delta * delta *
                        (d_k1 * root * root + 2.0f * delta * th1m + d_k * (1.0f - root) * (1.0f - root));
                    const float lad = logf(num) - 2.0f * logf(den);
                    contrib -= lad;
                }
            }
        }
    }
    if (lane == 0)
        atomicAdd(&acc[((blockIdx.x << 3) | w) & 127], (double)contrib);
}

// ---------------------------------------------------------------- Poisson counts term
__global__ __launch_bounds__(256) void ll_counts_kernel(
    const float* __restrict__ h, const float* __restrict__ rho_w,
    const float* __restrict__ rho_bias, const float* __restrict__ libsize,
    const int* __restrict__ genes_oi, const int* __restrict__ cells_oi,
    const int* __restrict__ counts, double* __restrict__ acc)
{
    int i = blockIdx.x * blockDim.x + threadIdx.x;
    float v = 0.f;
    if (i < N_PAIR) {
        const int c = i / N_GOI;
        const int gl = i - c * N_GOI;
        const int g = genes_oi[gl];
        float rho = 0.f;
        #pragma unroll
        for (int j = 0; j < N_HIDK; ++j)
            rho = fmaf(h[c * N_HIDK + j], rho_w[g * N_HIDK + j], rho);
        const float rate = rho_bias[g] * expf(rho) * libsize[cells_oi[c]];
        const float cnt = (float)counts[i];
        v = cnt * logf(rate) - rate - lgammaf(cnt + 1.0f);
    }
    #pragma unroll
    for (int o = 32; o; o >>= 1) v += __shfl_xor(v, o);
    if ((threadIdx.x & 63) == 0)
        atomicAdd(&acc[128 + (((blockIdx.x << 2) | (threadIdx.x >> 6)) & 63)], (double)v);
}

// ---------------------------------------------------------------- finalize (one wave)
__global__ __launch_bounds__(64) void final_kernel(const double* __restrict__ acc,
                                                   float* __restrict__ out)
{
    const int lane = threadIdx.x;
    double s = acc[lane] + acc[lane + 64] + acc[lane + 128];
    #pragma unroll
    for (int o = 32; o; o >>= 1) s += __shfl_down(s, o);
    if (lane == 0) {
        const double c0 = (double)(2 * N_FRAGK) * (log(0.5) - log((double)AB_F));
        out[0] = (float)(-(s + c0));
    }
}

// ---------------------------------------------------------------- launch
extern "C" void kernel_launch(void* const* d_in, const int* in_sizes, int n_in,
                              void* d_out, int out_size, void* d_ws, size_t ws_size,
                              hipStream_t stream)
{
    const float* latent   = (const float*)d_in[0];
    const float* coords   = (const float*)d_in[1];
    const float* W1       = (const float*)d_in[2];
    const float* b1       = (const float*)d_in[3];
    const float* g1       = (const float*)d_in[4];
    const float* be1      = (const float*)d_in[5];
    const float* W2       = (const float*)d_in[6];
    const float* b2       = (const float*)d_in[7];
    const float* g2       = (const float*)d_in[8];
    const float* be2      = (const float*)d_in[9];
    const float* spline_w = (const float*)d_in[10];
    const float* rho_w    = (const float*)d_in[11];
    const float* mix      = (const float*)d_in[12];
    const float* rho_bias = (const float*)d_in[13];
    const float* libsize  = (const float*)d_in[14];
    const int* genes_oi   = (const int*)d_in[15];
    const int* cells_oi   = (const int*)d_in[16];
    const int* lcx        = (const int*)d_in[17];

    char* ws = (char*)d_ws;
    int*    hist   = (int*)(ws + WS_HIST);
    double* acc    = (double*)(ws + WS_ACC);
    float*  h_ws   = (float*)(ws + WS_H);
    int*    off    = (int*)(ws + WS_OFF);
    int*    cur    = (int*)(ws + WS_CUR);
    int*    sorted = (int*)(ws + WS_SORT);

    hipMemsetAsync(d_ws, 0, WS_ZERO, stream);   // hist + acc

    hipLaunchKernelGGL(mlp_hist_kernel, dim3(HIST_BLOCKS + 1), dim3(256), 0, stream,
                       latent, W1, b1, g1, be1, W2, b2, g2, be2, h_ws, lcx, hist);
    hipLaunchKernelGGL(scan_kernel, dim3(1), dim3(1024), 0, stream, hist, off, cur);
    hipLaunchKernelGGL(scatter_kernel, dim3((N_FRAGK + 255) / 256), dim3(256), 0, stream,
                       lcx, cur, sorted);
    hipLaunchKernelGGL(gene_kernel, dim3(N_GOI * N_TILES), dim3(512), 0, stream,
                       h_ws, spline_w, mix, genes_oi, coords, off, sorted, acc);
    hipLaunchKernelGGL(ll_counts_kernel, dim3((N_PAIR + 255) / 256), dim3(256), 0, stream,
                       h_ws, rho_w, rho_bias, libsize, genes_oi, cells_oi, hist, acc);
    hipLaunchKernelGGL(final_kernel, dim3(1), dim3(64), 0, stream, acc, (float*)d_out);
}